// Round 2
// baseline (352.154 us; speedup 1.0000x reference)
//
#include <hip/hip_runtime.h>
#include <stdint.h>

// ---------------------------------------------------------------------------
// CausalSelfAttention: x[4,2048,1024] fp32 -> out fp32
// bf16 MFMA (16x16x32) everywhere, fp32 accum.
// R9: attn = K/V LDS double-buffer -> ONE barrier per k-iter; staging writes
//     into buf^1 overlap compute from buf (T14 analog). ks-split P-write/PV
//     to shorten the exp2->P->PV LDS chain. s_setprio(1) around MFMA
//     clusters (T5). Uniform-work q-tile pairing (pr,15-pr), conflict-free
//     staging, ones-fragment row-sum, builtin exp2, scale folded into Q.
// (R10 resubmit: R9 bench was an infra failure — container acquisition —
//  no kernel-attributable evidence; same source.)
// ---------------------------------------------------------------------------

typedef float  floatx4 __attribute__((ext_vector_type(4)));
typedef __bf16 bf16x8  __attribute__((ext_vector_type(8)));
typedef __bf16 bf16x4  __attribute__((ext_vector_type(4)));

#define AS1 __attribute__((address_space(1)))
#define AS3 __attribute__((address_space(3)))

__device__ __forceinline__ void gload_lds16(const void* g, void* l) {
    __builtin_amdgcn_global_load_lds((AS1 void*)(uintptr_t)g,
                                     (AS3 void*)(uintptr_t)l, 16, 0, 0);
}

#if __has_builtin(__builtin_amdgcn_exp2f)
#define EXP2F(x) __builtin_amdgcn_exp2f(x)   // raw v_exp_f32
#else
#define EXP2F(x) exp2f(x)
#endif

#define LOG2E 1.44269504088896340736f
#define ATT_SC (0.125f * LOG2E)   // softmax scale folded into Q at GEMM1
#define MASK_NEG (-3.0e4f)        // exp2(-3e4) == 0, safely finite

static constexpr int Bn = 4, Tn = 2048, Cn = 1024, Hn = 16, DKn = 64;
static constexpr int BT = Bn * Tn;          // 8192
static constexpr int N_QKV = 3 * Cn;        // 3072
static constexpr int PAD = 68;              // LDS row pad (bf16 elems)

// ------------------------- cast / transpose kernels ------------------------

__global__ void cast_x_kernel(const float* __restrict__ x, __bf16* __restrict__ xb, int n) {
    int i = (blockIdx.x * blockDim.x + threadIdx.x) * 4;
    if (i < n) {
        float4 v = *(const float4*)(x + i);
        bf16x4 o;
        o[0] = (__bf16)v.x; o[1] = (__bf16)v.y; o[2] = (__bf16)v.z; o[3] = (__bf16)v.w;
        *(bf16x4*)(xb + i) = o;
    }
}

// W [R][C] fp32 -> WT [C][R] bf16
__global__ void transpose_cast_kernel(const float* __restrict__ W, __bf16* __restrict__ WT,
                                      int R, int C) {
    __shared__ float tile[32][33];
    int tx = threadIdx.x & 31, ty = threadIdx.x >> 5;  // 32 x 8
    int r0 = blockIdx.y * 32, c0 = blockIdx.x * 32;
#pragma unroll
    for (int i = 0; i < 4; i++)
        tile[ty + i * 8][tx] = W[(size_t)(r0 + ty + i * 8) * C + c0 + tx];
    __syncthreads();
#pragma unroll
    for (int i = 0; i < 4; i++)
        WT[(size_t)(c0 + ty + i * 8) * R + r0 + tx] = (__bf16)tile[tx][ty + i * 8];
}

// ------------------------------- GEMM 1 ------------------------------------
// C[8192,3072] = A[8192,1024] @ Bt[3072,1024]^T + bias.
// Q (pre-scaled by ATT_SC), K -> head-major [b][h][t][64];
// V -> TRANSPOSED head-major [b][h][64][t].
__global__ __launch_bounds__(256) void gemm_qkv_kernel(
    const __bf16* __restrict__ A, const __bf16* __restrict__ Bt,
    const float* __restrict__ bias,
    __bf16* __restrict__ Qo, __bf16* __restrict__ Ko, __bf16* __restrict__ Vo) {
    const int K = 1024;
    __shared__ __bf16 Al[128 * 32];
    __shared__ __bf16 Bl[128 * 32];
    int tid = threadIdx.x, w = tid >> 6, lane = tid & 63;
    int lq = lane >> 4, l16 = lane & 15;
    int bm = blockIdx.y, bn = blockIdx.x;
    int wm = w & 1, wn = w >> 1;  // 2x2 waves -> 64x64 each

    const __bf16* Ag = A + (size_t)(bm * 128 + w * 32 + (lane >> 2)) * K + (lane & 3) * 8;
    const __bf16* Bg = Bt + (size_t)(bn * 128 + w * 32 + (lane >> 2)) * K + (lane & 3) * 8;
    __bf16* AlW = Al + w * 32 * 32;
    __bf16* BlW = Bl + w * 32 * 32;

    floatx4 acc[4][4] = {};
    for (int k0 = 0; k0 < K; k0 += 32) {
        __syncthreads();
        gload_lds16(Ag + k0, AlW);
        gload_lds16(Ag + k0 + 16 * K, AlW + 16 * 32);
        gload_lds16(Bg + k0, BlW);
        gload_lds16(Bg + k0 + 16 * K, BlW + 16 * 32);
        __syncthreads();
        bf16x8 af[4], bf[4];
#pragma unroll
        for (int i = 0; i < 4; i++)
            af[i] = *(const bf16x8*)&Al[(wm * 64 + i * 16 + l16) * 32 + lq * 8];
#pragma unroll
        for (int i = 0; i < 4; i++)
            bf[i] = *(const bf16x8*)&Bl[(wn * 64 + i * 16 + l16) * 32 + lq * 8];
#pragma unroll
        for (int mt = 0; mt < 4; mt++)
#pragma unroll
            for (int nt = 0; nt < 4; nt++)
                acc[mt][nt] = __builtin_amdgcn_mfma_f32_16x16x32_bf16(
                    af[mt], bf[nt], acc[mt][nt], 0, 0, 0);
    }
    // epilogue: C/D layout col=l16, row=lq*4+r.
#pragma unroll
    for (int nt = 0; nt < 4; nt++) {
        int gbase = bn * 128 + wn * 64 + nt * 16;  // wave-uniform, 16-aligned
        int gcol = gbase + l16;
        int which = gbase >> 10;                   // uniform (1024 % 16 == 0)
        float bv = bias[gcol];
        if (which == 2) {
            // V transposed: [b][h][64 d][2048 t], 4 consecutive t per lane.
            int hh = (gbase - 2048) >> 6;
            int dd = ((gbase - 2048) & 63) + l16;
#pragma unroll
            for (int mt = 0; mt < 4; mt++) {
                int growb = bm * 128 + wm * 64 + mt * 16 + lq * 4;
                int bb = growb >> 11, tt = growb & 2047;
                bf16x4 v4;
#pragma unroll
                for (int r = 0; r < 4; r++) v4[r] = (__bf16)(acc[mt][nt][r] + bv);
                *(bf16x4*)&Vo[((size_t)(bb * 16 + hh) * 64 + dd) * 2048 + tt] = v4;
            }
        } else {
            int rem = gbase & 1023;
            int hh = rem >> 6, dd = (rem & 63) + l16;
            __bf16* dst = (which == 0) ? Qo : Ko;
            float scl = (which == 0) ? ATT_SC : 1.0f;  // fold softmax scale into Q
#pragma unroll
            for (int mt = 0; mt < 4; mt++) {
#pragma unroll
                for (int r = 0; r < 4; r++) {
                    int grow = bm * 128 + wm * 64 + mt * 16 + lq * 4 + r;
                    int bb = grow >> 11, tt = grow & 2047;
                    dst[((size_t)(bb * 16 + hh) * 2048 + tt) * 64 + dd] =
                        (__bf16)((acc[mt][nt][r] + bv) * scl);
                }
            }
        }
    }
}

// ------------------------------- GEMM 2 ------------------------------------
__global__ __launch_bounds__(256) void gemm_proj_kernel(
    const __bf16* __restrict__ A, const __bf16* __restrict__ Bt,
    const float* __restrict__ bias, float* __restrict__ out) {
    const int K = 1024;
    __shared__ __bf16 Al[128 * 32];
    __shared__ __bf16 Bl[128 * 32];
    int tid = threadIdx.x, w = tid >> 6, lane = tid & 63;
    int lq = lane >> 4, l16 = lane & 15;
    int bm = blockIdx.y, bn = blockIdx.x;
    int wm = w & 1, wn = w >> 1;

    const __bf16* Ag = A + (size_t)(bm * 128 + w * 32 + (lane >> 2)) * K + (lane & 3) * 8;
    const __bf16* Bg = Bt + (size_t)(bn * 128 + w * 32 + (lane >> 2)) * K + (lane & 3) * 8;
    __bf16* AlW = Al + w * 32 * 32;
    __bf16* BlW = Bl + w * 32 * 32;

    floatx4 acc[4][4] = {};
    for (int k0 = 0; k0 < K; k0 += 32) {
        __syncthreads();
        gload_lds16(Ag + k0, AlW);
        gload_lds16(Ag + k0 + 16 * K, AlW + 16 * 32);
        gload_lds16(Bg + k0, BlW);
        gload_lds16(Bg + k0 + 16 * K, BlW + 16 * 32);
        __syncthreads();
        bf16x8 af[4], bf[4];
#pragma unroll
        for (int i = 0; i < 4; i++)
            af[i] = *(const bf16x8*)&Al[(wm * 64 + i * 16 + l16) * 32 + lq * 8];
#pragma unroll
        for (int i = 0; i < 4; i++)
            bf[i] = *(const bf16x8*)&Bl[(wn * 64 + i * 16 + l16) * 32 + lq * 8];
#pragma unroll
        for (int mt = 0; mt < 4; mt++)
#pragma unroll
            for (int nt = 0; nt < 4; nt++)
                acc[mt][nt] = __builtin_amdgcn_mfma_f32_16x16x32_bf16(
                    af[mt], bf[nt], acc[mt][nt], 0, 0, 0);
    }
#pragma unroll
    for (int nt = 0; nt < 4; nt++) {
        int gcol = bn * 128 + wn * 64 + nt * 16 + l16;
        float bv = bias[gcol];
#pragma unroll
        for (int mt = 0; mt < 4; mt++) {
#pragma unroll
            for (int r = 0; r < 4; r++) {
                int grow = bm * 128 + wm * 64 + mt * 16 + lq * 4 + r;
                out[(size_t)grow * 1024 + gcol] = acc[mt][nt][r] + bv;
            }
        }
    }
}

// ---------------------------- flash attention ------------------------------
// grid: flat 512, block 256 (4 waves). Block bid handles bh = bid&63 and the
// q-tile PAIR (pr, 15-pr), pr = bid>>6, sequentially (128-row tiles).
// Flat pipeline over 34 k-iterations (uniform across grid):
//   regs always hold tile f+1; each iter: barrier -> write regs into
//   buf[par^1] (overlaps compute) -> issue loads tile f+2 -> compute buf[par].
// ONE barrier per iteration (double-buffered K/V).
// Q pre-scaled so p = exp2(s). Row-sum via all-ones B-fragment.
// Staging: srow=tid>>3 — each 16-lane group covers whole padded rows
// (conflict-free, R2-measured 0).
__global__ __launch_bounds__(256) void attn_kernel(
    const __bf16* __restrict__ Q, const __bf16* __restrict__ K,
    const __bf16* __restrict__ Vt, __bf16* __restrict__ Y) {
    const int bid = blockIdx.x;
    const int pr = bid >> 6, bh = bid & 63;
    const int b = bh >> 4, h = bh & 15;
    int tid = threadIdx.x, w = tid >> 6, lane = tid & 63;
    int lq = lane >> 4, l16 = lane & 15;

    const __bf16* Qh = Q + (size_t)bh * Tn * DKn;
    const __bf16* Kh = K + (size_t)bh * Tn * DKn;
    const __bf16* Vh = Vt + (size_t)bh * DKn * Tn;  // [64 d][2048 t]

    __shared__ __bf16 Kl[2][64 * PAD];   // [key][d], double-buffered
    __shared__ __bf16 Vl[2][64 * PAD];   // [d][key], double-buffered
    __shared__ __bf16 Pl[128 * PAD];     // P: C-layout write, A-layout read

    int srow = tid >> 3, ssl = tid & 7;  // rows 0..31 (+32 for second chunk)

    bf16x8 onesf;
#pragma unroll
    for (int j = 0; j < 8; j++) onesf[j] = (__bf16)1.0f;

    const int km0 = 2 * pr + 1;  // last flat iter of segment 0
    const int NT = 34;           // total flat iters: (2*pr+2) + (2*(15-pr)+2)

    // k-tile index of flat iteration f
#define KTILE(ff) ((ff) <= km0 ? (ff) : (ff) - km0 - 1)

    // prologue: T0 -> regs -> buf0 ; T1 -> regs
    bf16x8 kr0 = *(const bf16x8*)&Kh[(size_t)srow * 64 + ssl * 8];
    bf16x8 kr1 = *(const bf16x8*)&Kh[(size_t)(srow + 32) * 64 + ssl * 8];
    bf16x8 vr0 = *(const bf16x8*)&Vh[(size_t)srow * 2048 + ssl * 8];
    bf16x8 vr1 = *(const bf16x8*)&Vh[(size_t)(srow + 32) * 2048 + ssl * 8];
    *(bf16x8*)&Kl[0][srow * PAD + ssl * 8] = kr0;
    *(bf16x8*)&Kl[0][(srow + 32) * PAD + ssl * 8] = kr1;
    *(bf16x8*)&Vl[0][srow * PAD + ssl * 8] = vr0;
    *(bf16x8*)&Vl[0][(srow + 32) * PAD + ssl * 8] = vr1;
    {
        int nk = KTILE(1);
        kr0 = *(const bf16x8*)&Kh[(size_t)(nk * 64 + srow) * 64 + ssl * 8];
        kr1 = *(const bf16x8*)&Kh[(size_t)(nk * 64 + srow + 32) * 64 + ssl * 8];
        vr0 = *(const bf16x8*)&Vh[(size_t)srow * 2048 + nk * 64 + ssl * 8];
        vr1 = *(const bf16x8*)&Vh[(size_t)(srow + 32) * 2048 + nk * 64 + ssl * 8];
    }

    int par = 0, f = 0;
#pragma unroll
    for (int seg = 0; seg < 2; seg++) {
        const int qt = seg ? (15 - pr) : pr;
        const int q0 = qt * 128;
        const int ktmax = 2 * qt + 1;

        // Q fragments for this segment
        bf16x8 qf[2][2];
#pragma unroll
        for (int mt = 0; mt < 2; mt++)
#pragma unroll
            for (int ks = 0; ks < 2; ks++)
                qf[mt][ks] = *(const bf16x8*)&Qh[(size_t)(q0 + w * 32 + mt * 16 + l16) * 64 +
                                                 ks * 32 + lq * 8];

        floatx4 oacc[2][5] = {};  // [mt][d-tile 0..3, 4 = row-sum]

        for (int kt = 0; kt <= ktmax; kt++, f++) {
            __syncthreads();  // buf[par] writes visible; buf[par^1] reads done
            if (f + 1 < NT) {
                // stage tile f+1 into the other buffer (overlaps compute below)
                __bf16* Kn = &Kl[par ^ 1][0];
                __bf16* Vn = &Vl[par ^ 1][0];
                *(bf16x8*)&Kn[srow * PAD + ssl * 8] = kr0;
                *(bf16x8*)&Kn[(srow + 32) * PAD + ssl * 8] = kr1;
                *(bf16x8*)&Vn[srow * PAD + ssl * 8] = vr0;
                *(bf16x8*)&Vn[(srow + 32) * PAD + ssl * 8] = vr1;
                if (f + 2 < NT) {
                    int nk = KTILE(f + 2);
                    kr0 = *(const bf16x8*)&Kh[(size_t)(nk * 64 + srow) * 64 + ssl * 8];
                    kr1 = *(const bf16x8*)&Kh[(size_t)(nk * 64 + srow + 32) * 64 + ssl * 8];
                    vr0 = *(const bf16x8*)&Vh[(size_t)srow * 2048 + nk * 64 + ssl * 8];
                    vr1 = *(const bf16x8*)&Vh[(size_t)(srow + 32) * 2048 + nk * 64 + ssl * 8];
                }
            }

            const __bf16* Kc = &Kl[par][0];
            const __bf16* Vc = &Vl[par][0];

            // S = Q @ K^T   (Q pre-scaled)
            floatx4 s2[2][4] = {};
#pragma unroll
            for (int ks = 0; ks < 2; ks++) {
                bf16x8 kf[4];
#pragma unroll
                for (int nt = 0; nt < 4; nt++)
                    kf[nt] = *(const bf16x8*)&Kc[(nt * 16 + l16) * PAD + ks * 32 + lq * 8];
                __builtin_amdgcn_s_setprio(1);
#pragma unroll
                for (int mt = 0; mt < 2; mt++)
#pragma unroll
                    for (int nt = 0; nt < 4; nt++)
                        s2[mt][nt] = __builtin_amdgcn_mfma_f32_16x16x32_bf16(
                            qf[mt][ks], kf[nt], s2[mt][nt], 0, 0, 0);
                __builtin_amdgcn_s_setprio(0);
            }

            // causal mask on the diagonal tiles
            if (kt >= 2 * qt) {
#pragma unroll
                for (int mt = 0; mt < 2; mt++)
#pragma unroll
                    for (int nt = 0; nt < 4; nt++) {
                        int col = kt * 64 + nt * 16 + l16;
#pragma unroll
                        for (int r = 0; r < 4; r++) {
                            int row = q0 + w * 32 + mt * 16 + lq * 4 + r;
                            if (col > row) s2[mt][nt][r] = MASK_NEG;
                        }
                    }
            }

            // ks-split: write P half, immediately consume it with PV half.
#pragma unroll
            for (int ks = 0; ks < 2; ks++) {
#pragma unroll
                for (int mt = 0; mt < 2; mt++) {
#pragma unroll
                    for (int nth = 0; nth < 2; nth++) {
                        int nt = ks * 2 + nth;
#pragma unroll
                        for (int r = 0; r < 4; r++) {
                            float p = EXP2F(s2[mt][nt][r]);
                            int rowl = w * 32 + mt * 16 + lq * 4 + r;
                            Pl[rowl * PAD + nt * 16 + l16] = (__bf16)p;
                        }
                    }
                }
                bf16x8 pf[2], vf[4];
#pragma unroll
                for (int mt = 0; mt < 2; mt++)
                    pf[mt] = *(const bf16x8*)&Pl[(w * 32 + mt * 16 + l16) * PAD + ks * 32 + lq * 8];
#pragma unroll
                for (int dt = 0; dt < 4; dt++)
                    vf[dt] = *(const bf16x8*)&Vc[(dt * 16 + l16) * PAD + ks * 32 + lq * 8];
                __builtin_amdgcn_s_setprio(1);
#pragma unroll
                for (int mt = 0; mt < 2; mt++) {
#pragma unroll
                    for (int dt = 0; dt < 4; dt++)
                        oacc[mt][dt] = __builtin_amdgcn_mfma_f32_16x16x32_bf16(
                            pf[mt], vf[dt], oacc[mt][dt], 0, 0, 0);
                    oacc[mt][4] = __builtin_amdgcn_mfma_f32_16x16x32_bf16(
                        pf[mt], onesf, oacc[mt][4], 0, 0, 0);
                }
                __builtin_amdgcn_s_setprio(0);
            }
            par ^= 1;
        }

        // epilogue for this segment: tile 4 columns hold the row-sum.
#pragma unroll
        for (int mt = 0; mt < 2; mt++) {
#pragma unroll
            for (int r = 0; r < 4; r++) {
                float inv = 1.0f / oacc[mt][4][r];
                int rowg = q0 + w * 32 + mt * 16 + lq * 4 + r;
#pragma unroll
                for (int dt = 0; dt < 4; dt++)
                    Y[((size_t)(b * 2048 + rowg)) * 1024 + h * 64 + dt * 16 + l16] =
                        (__bf16)(oacc[mt][dt][r] * inv);
            }
        }
    }
#undef KTILE
}

// ------------------------------- launcher ----------------------------------

extern "C" void kernel_launch(void* const* d_in, const int* in_sizes, int n_in,
                              void* d_out, int out_size, void* d_ws, size_t ws_size,
                              hipStream_t stream) {
    const float* x     = (const float*)d_in[0];
    const float* Wqkv  = (const float*)d_in[1];
    const float* bqkv  = (const float*)d_in[2];
    const float* Wproj = (const float*)d_in[3];
    const float* bproj = (const float*)d_in[4];
    float* out = (float*)d_out;

    __bf16* xb     = (__bf16*)d_ws;                       // 8192*1024
    __bf16* WqkvT  = xb + (size_t)BT * Cn;                // 3072*1024
    __bf16* WprojT = WqkvT + (size_t)N_QKV * Cn;          // 1024*1024
    __bf16* Qb     = WprojT + (size_t)Cn * Cn;            // [b][h][t][64], pre-scaled
    __bf16* Kb     = Qb + (size_t)BT * Cn;                // [b][h][t][64]
    __bf16* Vb     = Kb + (size_t)BT * Cn;                // [b][h][64][t] (transposed)
    __bf16* Yb     = Vb + (size_t)BT * Cn;                // 8192*1024

    int nx = BT * Cn;
    cast_x_kernel<<<(nx / 4 + 255) / 256, 256, 0, stream>>>(x, xb, nx);
    transpose_cast_kernel<<<dim3(N_QKV / 32, Cn / 32), 256, 0, stream>>>(Wqkv, WqkvT, Cn, N_QKV);
    transpose_cast_kernel<<<dim3(Cn / 32, Cn / 32), 256, 0, stream>>>(Wproj, WprojT, Cn, Cn);

    gemm_qkv_kernel<<<dim3(N_QKV / 128, BT / 128), 256, 0, stream>>>(
        xb, WqkvT, bqkv, Qb, Kb, Vb);

    attn_kernel<<<dim3(512), 256, 0, stream>>>(Qb, Kb, Vb, Yb);

    gemm_proj_kernel<<<dim3(Cn / 128, BT / 128), 256, 0, stream>>>(
        Yb, WprojT, bproj, out);
}

// Round 3
// 257.057 us; speedup vs baseline: 1.3699x; 1.3699x over previous
//
#include <hip/hip_runtime.h>
#include <stdint.h>

// ---------------------------------------------------------------------------
// CausalSelfAttention: x[4,2048,1024] fp32 -> out fp32
// bf16 MFMA (16x16x32) everywhere, fp32 accum.
// R11: attn REVERTED to exact R8 structure (75.9us measured; R9's
//      dbuf+setprio+ks-split rewrite regressed 2.26x, mechanism unresolved —
//      see journal). Single new change this round: T1 XCD-aware block swizzle
//      on both GEMMs (bijective, nwg%8==0) for A-panel L2 locality.
// ---------------------------------------------------------------------------

typedef float  floatx4 __attribute__((ext_vector_type(4)));
typedef __bf16 bf16x8  __attribute__((ext_vector_type(8)));
typedef __bf16 bf16x4  __attribute__((ext_vector_type(4)));

#define AS1 __attribute__((address_space(1)))
#define AS3 __attribute__((address_space(3)))

__device__ __forceinline__ void gload_lds16(const void* g, void* l) {
    __builtin_amdgcn_global_load_lds((AS1 void*)(uintptr_t)g,
                                     (AS3 void*)(uintptr_t)l, 16, 0, 0);
}

#if __has_builtin(__builtin_amdgcn_exp2f)
#define EXP2F(x) __builtin_amdgcn_exp2f(x)   // raw v_exp_f32
#else
#define EXP2F(x) exp2f(x)
#endif

#define LOG2E 1.44269504088896340736f
#define ATT_SC (0.125f * LOG2E)   // softmax scale folded into Q at GEMM1
#define MASK_NEG (-3.0e4f)        // exp2(-3e4) == 0, safely finite

static constexpr int Bn = 4, Tn = 2048, Cn = 1024, Hn = 16, DKn = 64;
static constexpr int BT = Bn * Tn;          // 8192
static constexpr int N_QKV = 3 * Cn;        // 3072
static constexpr int PAD = 68;              // LDS row pad (bf16 elems)

// ------------------------- cast / transpose kernels ------------------------

__global__ void cast_x_kernel(const float* __restrict__ x, __bf16* __restrict__ xb, int n) {
    int i = (blockIdx.x * blockDim.x + threadIdx.x) * 4;
    if (i < n) {
        float4 v = *(const float4*)(x + i);
        bf16x4 o;
        o[0] = (__bf16)v.x; o[1] = (__bf16)v.y; o[2] = (__bf16)v.z; o[3] = (__bf16)v.w;
        *(bf16x4*)(xb + i) = o;
    }
}

// W [R][C] fp32 -> WT [C][R] bf16
__global__ void transpose_cast_kernel(const float* __restrict__ W, __bf16* __restrict__ WT,
                                      int R, int C) {
    __shared__ float tile[32][33];
    int tx = threadIdx.x & 31, ty = threadIdx.x >> 5;  // 32 x 8
    int r0 = blockIdx.y * 32, c0 = blockIdx.x * 32;
#pragma unroll
    for (int i = 0; i < 4; i++)
        tile[ty + i * 8][tx] = W[(size_t)(r0 + ty + i * 8) * C + c0 + tx];
    __syncthreads();
#pragma unroll
    for (int i = 0; i < 4; i++)
        WT[(size_t)(c0 + ty + i * 8) * R + r0 + tx] = (__bf16)tile[tx][ty + i * 8];
}

// T1: bijective XCD-aware remap of the flattened block id. nwg % 8 == 0 for
// both GEMMs (1536, 512). Default dispatch: XCD = flat % 8; after remap each
// XCD executes a contiguous chunk of work ids -> same-bm blocks (sharing an
// A-panel) land on one XCD's L2.
__device__ __forceinline__ void xcd_swizzle(int gx, int* bn, int* bm) {
    int flat = blockIdx.y * gx + blockIdx.x;
    int nwg = gx * gridDim.y;
    int cpx = nwg >> 3;
    int swz = (flat & 7) * cpx + (flat >> 3);
    *bm = swz / gx;
    *bn = swz - *bm * gx;
}

// ------------------------------- GEMM 1 ------------------------------------
// C[8192,3072] = A[8192,1024] @ Bt[3072,1024]^T + bias.
// Q (pre-scaled by ATT_SC), K -> head-major [b][h][t][64];
// V -> TRANSPOSED head-major [b][h][64][t].
__global__ __launch_bounds__(256) void gemm_qkv_kernel(
    const __bf16* __restrict__ A, const __bf16* __restrict__ Bt,
    const float* __restrict__ bias,
    __bf16* __restrict__ Qo, __bf16* __restrict__ Ko, __bf16* __restrict__ Vo) {
    const int K = 1024;
    __shared__ __bf16 Al[128 * 32];
    __shared__ __bf16 Bl[128 * 32];
    int tid = threadIdx.x, w = tid >> 6, lane = tid & 63;
    int lq = lane >> 4, l16 = lane & 15;
    int bm, bn;
    xcd_swizzle(gridDim.x, &bn, &bm);
    int wm = w & 1, wn = w >> 1;  // 2x2 waves -> 64x64 each

    const __bf16* Ag = A + (size_t)(bm * 128 + w * 32 + (lane >> 2)) * K + (lane & 3) * 8;
    const __bf16* Bg = Bt + (size_t)(bn * 128 + w * 32 + (lane >> 2)) * K + (lane & 3) * 8;
    __bf16* AlW = Al + w * 32 * 32;
    __bf16* BlW = Bl + w * 32 * 32;

    floatx4 acc[4][4] = {};
    for (int k0 = 0; k0 < K; k0 += 32) {
        __syncthreads();
        gload_lds16(Ag + k0, AlW);
        gload_lds16(Ag + k0 + 16 * K, AlW + 16 * 32);
        gload_lds16(Bg + k0, BlW);
        gload_lds16(Bg + k0 + 16 * K, BlW + 16 * 32);
        __syncthreads();
        bf16x8 af[4], bf[4];
#pragma unroll
        for (int i = 0; i < 4; i++)
            af[i] = *(const bf16x8*)&Al[(wm * 64 + i * 16 + l16) * 32 + lq * 8];
#pragma unroll
        for (int i = 0; i < 4; i++)
            bf[i] = *(const bf16x8*)&Bl[(wn * 64 + i * 16 + l16) * 32 + lq * 8];
#pragma unroll
        for (int mt = 0; mt < 4; mt++)
#pragma unroll
            for (int nt = 0; nt < 4; nt++)
                acc[mt][nt] = __builtin_amdgcn_mfma_f32_16x16x32_bf16(
                    af[mt], bf[nt], acc[mt][nt], 0, 0, 0);
    }
    // epilogue: C/D layout col=l16, row=lq*4+r.
#pragma unroll
    for (int nt = 0; nt < 4; nt++) {
        int gbase = bn * 128 + wn * 64 + nt * 16;  // wave-uniform, 16-aligned
        int gcol = gbase + l16;
        int which = gbase >> 10;                   // uniform (1024 % 16 == 0)
        float bv = bias[gcol];
        if (which == 2) {
            // V transposed: [b][h][64 d][2048 t], 4 consecutive t per lane.
            int hh = (gbase - 2048) >> 6;
            int dd = ((gbase - 2048) & 63) + l16;
#pragma unroll
            for (int mt = 0; mt < 4; mt++) {
                int growb = bm * 128 + wm * 64 + mt * 16 + lq * 4;
                int bb = growb >> 11, tt = growb & 2047;
                bf16x4 v4;
#pragma unroll
                for (int r = 0; r < 4; r++) v4[r] = (__bf16)(acc[mt][nt][r] + bv);
                *(bf16x4*)&Vo[((size_t)(bb * 16 + hh) * 64 + dd) * 2048 + tt] = v4;
            }
        } else {
            int rem = gbase & 1023;
            int hh = rem >> 6, dd = (rem & 63) + l16;
            __bf16* dst = (which == 0) ? Qo : Ko;
            float scl = (which == 0) ? ATT_SC : 1.0f;  // fold softmax scale into Q
#pragma unroll
            for (int mt = 0; mt < 4; mt++) {
#pragma unroll
                for (int r = 0; r < 4; r++) {
                    int grow = bm * 128 + wm * 64 + mt * 16 + lq * 4 + r;
                    int bb = grow >> 11, tt = grow & 2047;
                    dst[((size_t)(bb * 16 + hh) * 2048 + tt) * 64 + dd] =
                        (__bf16)((acc[mt][nt][r] + bv) * scl);
                }
            }
        }
    }
}

// ------------------------------- GEMM 2 ------------------------------------
__global__ __launch_bounds__(256) void gemm_proj_kernel(
    const __bf16* __restrict__ A, const __bf16* __restrict__ Bt,
    const float* __restrict__ bias, float* __restrict__ out) {
    const int K = 1024;
    __shared__ __bf16 Al[128 * 32];
    __shared__ __bf16 Bl[128 * 32];
    int tid = threadIdx.x, w = tid >> 6, lane = tid & 63;
    int lq = lane >> 4, l16 = lane & 15;
    int bm, bn;
    xcd_swizzle(gridDim.x, &bn, &bm);
    int wm = w & 1, wn = w >> 1;

    const __bf16* Ag = A + (size_t)(bm * 128 + w * 32 + (lane >> 2)) * K + (lane & 3) * 8;
    const __bf16* Bg = Bt + (size_t)(bn * 128 + w * 32 + (lane >> 2)) * K + (lane & 3) * 8;
    __bf16* AlW = Al + w * 32 * 32;
    __bf16* BlW = Bl + w * 32 * 32;

    floatx4 acc[4][4] = {};
    for (int k0 = 0; k0 < K; k0 += 32) {
        __syncthreads();
        gload_lds16(Ag + k0, AlW);
        gload_lds16(Ag + k0 + 16 * K, AlW + 16 * 32);
        gload_lds16(Bg + k0, BlW);
        gload_lds16(Bg + k0 + 16 * K, BlW + 16 * 32);
        __syncthreads();
        bf16x8 af[4], bf[4];
#pragma unroll
        for (int i = 0; i < 4; i++)
            af[i] = *(const bf16x8*)&Al[(wm * 64 + i * 16 + l16) * 32 + lq * 8];
#pragma unroll
        for (int i = 0; i < 4; i++)
            bf[i] = *(const bf16x8*)&Bl[(wn * 64 + i * 16 + l16) * 32 + lq * 8];
#pragma unroll
        for (int mt = 0; mt < 4; mt++)
#pragma unroll
            for (int nt = 0; nt < 4; nt++)
                acc[mt][nt] = __builtin_amdgcn_mfma_f32_16x16x32_bf16(
                    af[mt], bf[nt], acc[mt][nt], 0, 0, 0);
    }
#pragma unroll
    for (int nt = 0; nt < 4; nt++) {
        int gcol = bn * 128 + wn * 64 + nt * 16 + l16;
        float bv = bias[gcol];
#pragma unroll
        for (int mt = 0; mt < 4; mt++) {
#pragma unroll
            for (int r = 0; r < 4; r++) {
                int grow = bm * 128 + wm * 64 + mt * 16 + lq * 4 + r;
                out[(size_t)grow * 1024 + gcol] = acc[mt][nt][r] + bv;
            }
        }
    }
}

// ---------------------------- flash attention ------------------------------
// grid: flat 512, block 256 (4 waves). Block bid handles bh = bid&63 and the
// q-tile PAIR (pr, 15-pr), pr = bid>>6, sequentially (128-row tiles).
// Per-block k-iterations = (2*pr+2) + (2*(15-pr)+2) = 34 — uniform across
// the whole grid, so no load-imbalance tail under any block placement.
// Q pre-scaled so p = exp2(s). Row-sum via all-ones B-fragment.
// K/V register-prefetch pipeline with cross-segment handoff.
// Staging: ci=tid+i*256, row=ci>>3 — each 16-lane group covers whole padded
// rows (conflict-free, R2-measured 0).
__global__ __launch_bounds__(256) void attn_kernel(
    const __bf16* __restrict__ Q, const __bf16* __restrict__ K,
    const __bf16* __restrict__ Vt, __bf16* __restrict__ Y) {
    const int bid = blockIdx.x;
    const int pr = bid >> 6, bh = bid & 63;
    const int b = bh >> 4, h = bh & 15;
    int tid = threadIdx.x, w = tid >> 6, lane = tid & 63;
    int lq = lane >> 4, l16 = lane & 15;

    const __bf16* Qh = Q + (size_t)bh * Tn * DKn;
    const __bf16* Kh = K + (size_t)bh * Tn * DKn;
    const __bf16* Vh = Vt + (size_t)bh * DKn * Tn;  // [64 d][2048 t]

    __shared__ __bf16 Kl[64 * PAD];   // [key][d]
    __shared__ __bf16 Vl[64 * PAD];   // [d][key]
    __shared__ __bf16 Pl[128 * PAD];  // P: C-layout write, A-layout read

    int srow = tid >> 3, ssl = tid & 7;  // rows 0..31 (+32 for second chunk)

    bf16x8 onesf;
#pragma unroll
    for (int j = 0; j < 8; j++) onesf[j] = (__bf16)1.0f;

    // prefetch k-tile 0 (shared by both segments' first iteration)
    bf16x8 kr0 = *(const bf16x8*)&Kh[(size_t)srow * 64 + ssl * 8];
    bf16x8 kr1 = *(const bf16x8*)&Kh[(size_t)(srow + 32) * 64 + ssl * 8];
    bf16x8 vr0 = *(const bf16x8*)&Vh[(size_t)srow * 2048 + ssl * 8];
    bf16x8 vr1 = *(const bf16x8*)&Vh[(size_t)(srow + 32) * 2048 + ssl * 8];

#pragma unroll
    for (int seg = 0; seg < 2; seg++) {
        const int qt = seg ? (15 - pr) : pr;
        const int q0 = qt * 128;
        const int ktmax = 2 * qt + 1;

        // Q fragments for this segment
        bf16x8 qf[2][2];
#pragma unroll
        for (int mt = 0; mt < 2; mt++)
#pragma unroll
            for (int ks = 0; ks < 2; ks++)
                qf[mt][ks] = *(const bf16x8*)&Qh[(size_t)(q0 + w * 32 + mt * 16 + l16) * 64 +
                                                 ks * 32 + lq * 8];

        floatx4 oacc[2][5] = {};  // [mt][d-tile 0..3, 4 = row-sum]

        for (int kt = 0; kt <= ktmax; kt++) {
            __syncthreads();  // all waves done reading Kl/Vl from previous iter
            *(bf16x8*)&Kl[srow * PAD + ssl * 8] = kr0;
            *(bf16x8*)&Kl[(srow + 32) * PAD + ssl * 8] = kr1;
            *(bf16x8*)&Vl[srow * PAD + ssl * 8] = vr0;
            *(bf16x8*)&Vl[(srow + 32) * PAD + ssl * 8] = vr1;
            __syncthreads();
            // prefetch next tile (next kt, or segment-B tile 0 at boundary)
            if (!(seg == 1 && kt == ktmax)) {
                int nk = (kt < ktmax) ? (kt + 1) : 0;
                kr0 = *(const bf16x8*)&Kh[(size_t)(nk * 64 + srow) * 64 + ssl * 8];
                kr1 = *(const bf16x8*)&Kh[(size_t)(nk * 64 + srow + 32) * 64 + ssl * 8];
                vr0 = *(const bf16x8*)&Vh[(size_t)srow * 2048 + nk * 64 + ssl * 8];
                vr1 = *(const bf16x8*)&Vh[(size_t)(srow + 32) * 2048 + nk * 64 + ssl * 8];
            }

            // S = Q @ K^T   (Q pre-scaled)
            floatx4 s2[2][4] = {};
#pragma unroll
            for (int ks = 0; ks < 2; ks++) {
                bf16x8 kf[4];
#pragma unroll
                for (int nt = 0; nt < 4; nt++)
                    kf[nt] = *(const bf16x8*)&Kl[(nt * 16 + l16) * PAD + ks * 32 + lq * 8];
#pragma unroll
                for (int mt = 0; mt < 2; mt++)
#pragma unroll
                    for (int nt = 0; nt < 4; nt++)
                        s2[mt][nt] = __builtin_amdgcn_mfma_f32_16x16x32_bf16(
                            qf[mt][ks], kf[nt], s2[mt][nt], 0, 0, 0);
            }

            // causal mask on the diagonal tiles
            if (kt >= 2 * qt) {
#pragma unroll
                for (int mt = 0; mt < 2; mt++)
#pragma unroll
                    for (int nt = 0; nt < 4; nt++) {
                        int col = kt * 64 + nt * 16 + l16;
#pragma unroll
                        for (int r = 0; r < 4; r++) {
                            int row = q0 + w * 32 + mt * 16 + lq * 4 + r;
                            if (col > row) s2[mt][nt][r] = MASK_NEG;
                        }
                    }
            }

            // p = exp2(s); write P (C-layout -> LDS, wave-private rows)
#pragma unroll
            for (int mt = 0; mt < 2; mt++) {
#pragma unroll
                for (int nt = 0; nt < 4; nt++) {
#pragma unroll
                    for (int r = 0; r < 4; r++) {
                        float p = EXP2F(s2[mt][nt][r]);
                        int rowl = w * 32 + mt * 16 + lq * 4 + r;
                        Pl[rowl * PAD + nt * 16 + l16] = (__bf16)p;
                    }
                }
            }

            // O += P @ [V | ones]
#pragma unroll
            for (int ks = 0; ks < 2; ks++) {
                bf16x8 pf[2], vf[4];
#pragma unroll
                for (int mt = 0; mt < 2; mt++)
                    pf[mt] = *(const bf16x8*)&Pl[(w * 32 + mt * 16 + l16) * PAD + ks * 32 + lq * 8];
#pragma unroll
                for (int dt = 0; dt < 4; dt++)
                    vf[dt] = *(const bf16x8*)&Vl[(dt * 16 + l16) * PAD + ks * 32 + lq * 8];
#pragma unroll
                for (int mt = 0; mt < 2; mt++) {
#pragma unroll
                    for (int dt = 0; dt < 4; dt++)
                        oacc[mt][dt] = __builtin_amdgcn_mfma_f32_16x16x32_bf16(
                            pf[mt], vf[dt], oacc[mt][dt], 0, 0, 0);
                    oacc[mt][4] = __builtin_amdgcn_mfma_f32_16x16x32_bf16(
                        pf[mt], onesf, oacc[mt][4], 0, 0, 0);
                }
            }
        }

        // epilogue for this segment: tile 4 columns hold the row-sum.
#pragma unroll
        for (int mt = 0; mt < 2; mt++) {
#pragma unroll
            for (int r = 0; r < 4; r++) {
                float inv = 1.0f / oacc[mt][4][r];
                int rowg = q0 + w * 32 + mt * 16 + lq * 4 + r;
#pragma unroll
                for (int dt = 0; dt < 4; dt++)
                    Y[((size_t)(b * 2048 + rowg)) * 1024 + h * 64 + dt * 16 + l16] =
                        (__bf16)(oacc[mt][dt][r] * inv);
            }
        }
    }
}

// ------------------------------- launcher ----------------------------------

extern "C" void kernel_launch(void* const* d_in, const int* in_sizes, int n_in,
                              void* d_out, int out_size, void* d_ws, size_t ws_size,
                              hipStream_t stream) {
    const float* x     = (const float*)d_in[0];
    const float* Wqkv  = (const float*)d_in[1];
    const float* bqkv  = (const float*)d_in[2];
    const float* Wproj = (const float*)d_in[3];
    const float* bproj = (const float*)d_in[4];
    float* out = (float*)d_out;

    __bf16* xb     = (__bf16*)d_ws;                       // 8192*1024
    __bf16* WqkvT  = xb + (size_t)BT * Cn;                // 3072*1024
    __bf16* WprojT = WqkvT + (size_t)N_QKV * Cn;          // 1024*1024
    __bf16* Qb     = WprojT + (size_t)Cn * Cn;            // [b][h][t][64], pre-scaled
    __bf16* Kb     = Qb + (size_t)BT * Cn;                // [b][h][t][64]
    __bf16* Vb     = Kb + (size_t)BT * Cn;                // [b][h][64][t] (transposed)
    __bf16* Yb     = Vb + (size_t)BT * Cn;                // 8192*1024

    int nx = BT * Cn;
    cast_x_kernel<<<(nx / 4 + 255) / 256, 256, 0, stream>>>(x, xb, nx);
    transpose_cast_kernel<<<dim3(N_QKV / 32, Cn / 32), 256, 0, stream>>>(Wqkv, WqkvT, Cn, N_QKV);
    transpose_cast_kernel<<<dim3(Cn / 32, Cn / 32), 256, 0, stream>>>(Wproj, WprojT, Cn, Cn);

    gemm_qkv_kernel<<<dim3(N_QKV / 128, BT / 128), 256, 0, stream>>>(
        xb, WqkvT, bqkv, Qb, Kb, Vb);

    attn_kernel<<<dim3(512), 256, 0, stream>>>(Qb, Kb, Vb, Yb);

    gemm_proj_kernel<<<dim3(Cn / 128, BT / 128), 256, 0, stream>>>(
        Yb, WprojT, bproj, out);
}

// Round 4
// 255.416 us; speedup vs baseline: 1.3787x; 1.0064x over previous
//
#include <hip/hip_runtime.h>
#include <stdint.h>

// ---------------------------------------------------------------------------
// CausalSelfAttention: x[4,2048,1024] fp32 -> out fp32
// bf16 MFMA (16x16x32) everywhere, fp32 accum.
// R12: attn KVBLK 64->128: stage 128 keys per two-barrier section, compute
//      two 64-key halves sequentially from the staged tile. Halves the
//      number of serial staging sections (34->17) and barriers (68->34)
//      while keeping the PROVEN R8 two-barrier skeleton (R9's single-barrier
//      +setprio rewrite regressed 2.26x and is abandoned). GEMMs keep the
//      R11 T1 XCD swizzle (260.7->257.1 confirmed).
// ---------------------------------------------------------------------------

typedef float  floatx4 __attribute__((ext_vector_type(4)));
typedef __bf16 bf16x8  __attribute__((ext_vector_type(8)));
typedef __bf16 bf16x4  __attribute__((ext_vector_type(4)));

#define AS1 __attribute__((address_space(1)))
#define AS3 __attribute__((address_space(3)))

__device__ __forceinline__ void gload_lds16(const void* g, void* l) {
    __builtin_amdgcn_global_load_lds((AS1 void*)(uintptr_t)g,
                                     (AS3 void*)(uintptr_t)l, 16, 0, 0);
}

#if __has_builtin(__builtin_amdgcn_exp2f)
#define EXP2F(x) __builtin_amdgcn_exp2f(x)   // raw v_exp_f32
#else
#define EXP2F(x) exp2f(x)
#endif

#define LOG2E 1.44269504088896340736f
#define ATT_SC (0.125f * LOG2E)   // softmax scale folded into Q at GEMM1
#define MASK_NEG (-3.0e4f)        // exp2(-3e4) == 0, safely finite

static constexpr int Bn = 4, Tn = 2048, Cn = 1024, Hn = 16, DKn = 64;
static constexpr int BT = Bn * Tn;          // 8192
static constexpr int N_QKV = 3 * Cn;        // 3072
static constexpr int PAD = 68;              // LDS row pad for 64-wide rows
static constexpr int VPAD = 132;            // LDS row pad for 128-wide rows

// ------------------------- cast / transpose kernels ------------------------

__global__ void cast_x_kernel(const float* __restrict__ x, __bf16* __restrict__ xb, int n) {
    int i = (blockIdx.x * blockDim.x + threadIdx.x) * 4;
    if (i < n) {
        float4 v = *(const float4*)(x + i);
        bf16x4 o;
        o[0] = (__bf16)v.x; o[1] = (__bf16)v.y; o[2] = (__bf16)v.z; o[3] = (__bf16)v.w;
        *(bf16x4*)(xb + i) = o;
    }
}

// W [R][C] fp32 -> WT [C][R] bf16
__global__ void transpose_cast_kernel(const float* __restrict__ W, __bf16* __restrict__ WT,
                                      int R, int C) {
    __shared__ float tile[32][33];
    int tx = threadIdx.x & 31, ty = threadIdx.x >> 5;  // 32 x 8
    int r0 = blockIdx.y * 32, c0 = blockIdx.x * 32;
#pragma unroll
    for (int i = 0; i < 4; i++)
        tile[ty + i * 8][tx] = W[(size_t)(r0 + ty + i * 8) * C + c0 + tx];
    __syncthreads();
#pragma unroll
    for (int i = 0; i < 4; i++)
        WT[(size_t)(c0 + ty + i * 8) * R + r0 + tx] = (__bf16)tile[tx][ty + i * 8];
}

// T1: bijective XCD-aware remap of the flattened block id. nwg % 8 == 0 for
// both GEMMs (1536, 512). Default dispatch: XCD = flat % 8; after remap each
// XCD executes a contiguous chunk of work ids -> same-bm blocks (sharing an
// A-panel) land on one XCD's L2.
__device__ __forceinline__ void xcd_swizzle(int gx, int* bn, int* bm) {
    int flat = blockIdx.y * gx + blockIdx.x;
    int nwg = gx * gridDim.y;
    int cpx = nwg >> 3;
    int swz = (flat & 7) * cpx + (flat >> 3);
    *bm = swz / gx;
    *bn = swz - *bm * gx;
}

// ------------------------------- GEMM 1 ------------------------------------
// C[8192,3072] = A[8192,1024] @ Bt[3072,1024]^T + bias.
// Q (pre-scaled by ATT_SC), K -> head-major [b][h][t][64];
// V -> TRANSPOSED head-major [b][h][64][t].
__global__ __launch_bounds__(256) void gemm_qkv_kernel(
    const __bf16* __restrict__ A, const __bf16* __restrict__ Bt,
    const float* __restrict__ bias,
    __bf16* __restrict__ Qo, __bf16* __restrict__ Ko, __bf16* __restrict__ Vo) {
    const int K = 1024;
    __shared__ __bf16 Al[128 * 32];
    __shared__ __bf16 Bl[128 * 32];
    int tid = threadIdx.x, w = tid >> 6, lane = tid & 63;
    int lq = lane >> 4, l16 = lane & 15;
    int bm, bn;
    xcd_swizzle(gridDim.x, &bn, &bm);
    int wm = w & 1, wn = w >> 1;  // 2x2 waves -> 64x64 each

    const __bf16* Ag = A + (size_t)(bm * 128 + w * 32 + (lane >> 2)) * K + (lane & 3) * 8;
    const __bf16* Bg = Bt + (size_t)(bn * 128 + w * 32 + (lane >> 2)) * K + (lane & 3) * 8;
    __bf16* AlW = Al + w * 32 * 32;
    __bf16* BlW = Bl + w * 32 * 32;

    floatx4 acc[4][4] = {};
    for (int k0 = 0; k0 < K; k0 += 32) {
        __syncthreads();
        gload_lds16(Ag + k0, AlW);
        gload_lds16(Ag + k0 + 16 * K, AlW + 16 * 32);
        gload_lds16(Bg + k0, BlW);
        gload_lds16(Bg + k0 + 16 * K, BlW + 16 * 32);
        __syncthreads();
        bf16x8 af[4], bf[4];
#pragma unroll
        for (int i = 0; i < 4; i++)
            af[i] = *(const bf16x8*)&Al[(wm * 64 + i * 16 + l16) * 32 + lq * 8];
#pragma unroll
        for (int i = 0; i < 4; i++)
            bf[i] = *(const bf16x8*)&Bl[(wn * 64 + i * 16 + l16) * 32 + lq * 8];
#pragma unroll
        for (int mt = 0; mt < 4; mt++)
#pragma unroll
            for (int nt = 0; nt < 4; nt++)
                acc[mt][nt] = __builtin_amdgcn_mfma_f32_16x16x32_bf16(
                    af[mt], bf[nt], acc[mt][nt], 0, 0, 0);
    }
    // epilogue: C/D layout col=l16, row=lq*4+r.
#pragma unroll
    for (int nt = 0; nt < 4; nt++) {
        int gbase = bn * 128 + wn * 64 + nt * 16;  // wave-uniform, 16-aligned
        int gcol = gbase + l16;
        int which = gbase >> 10;                   // uniform (1024 % 16 == 0)
        float bv = bias[gcol];
        if (which == 2) {
            // V transposed: [b][h][64 d][2048 t], 4 consecutive t per lane.
            int hh = (gbase - 2048) >> 6;
            int dd = ((gbase - 2048) & 63) + l16;
#pragma unroll
            for (int mt = 0; mt < 4; mt++) {
                int growb = bm * 128 + wm * 64 + mt * 16 + lq * 4;
                int bb = growb >> 11, tt = growb & 2047;
                bf16x4 v4;
#pragma unroll
                for (int r = 0; r < 4; r++) v4[r] = (__bf16)(acc[mt][nt][r] + bv);
                *(bf16x4*)&Vo[((size_t)(bb * 16 + hh) * 64 + dd) * 2048 + tt] = v4;
            }
        } else {
            int rem = gbase & 1023;
            int hh = rem >> 6, dd = (rem & 63) + l16;
            __bf16* dst = (which == 0) ? Qo : Ko;
            float scl = (which == 0) ? ATT_SC : 1.0f;  // fold softmax scale into Q
#pragma unroll
            for (int mt = 0; mt < 4; mt++) {
#pragma unroll
                for (int r = 0; r < 4; r++) {
                    int grow = bm * 128 + wm * 64 + mt * 16 + lq * 4 + r;
                    int bb = grow >> 11, tt = grow & 2047;
                    dst[((size_t)(bb * 16 + hh) * 2048 + tt) * 64 + dd] =
                        (__bf16)((acc[mt][nt][r] + bv) * scl);
                }
            }
        }
    }
}

// ------------------------------- GEMM 2 ------------------------------------
__global__ __launch_bounds__(256) void gemm_proj_kernel(
    const __bf16* __restrict__ A, const __bf16* __restrict__ Bt,
    const float* __restrict__ bias, float* __restrict__ out) {
    const int K = 1024;
    __shared__ __bf16 Al[128 * 32];
    __shared__ __bf16 Bl[128 * 32];
    int tid = threadIdx.x, w = tid >> 6, lane = tid & 63;
    int lq = lane >> 4, l16 = lane & 15;
    int bm, bn;
    xcd_swizzle(gridDim.x, &bn, &bm);
    int wm = w & 1, wn = w >> 1;

    const __bf16* Ag = A + (size_t)(bm * 128 + w * 32 + (lane >> 2)) * K + (lane & 3) * 8;
    const __bf16* Bg = Bt + (size_t)(bn * 128 + w * 32 + (lane >> 2)) * K + (lane & 3) * 8;
    __bf16* AlW = Al + w * 32 * 32;
    __bf16* BlW = Bl + w * 32 * 32;

    floatx4 acc[4][4] = {};
    for (int k0 = 0; k0 < K; k0 += 32) {
        __syncthreads();
        gload_lds16(Ag + k0, AlW);
        gload_lds16(Ag + k0 + 16 * K, AlW + 16 * 32);
        gload_lds16(Bg + k0, BlW);
        gload_lds16(Bg + k0 + 16 * K, BlW + 16 * 32);
        __syncthreads();
        bf16x8 af[4], bf[4];
#pragma unroll
        for (int i = 0; i < 4; i++)
            af[i] = *(const bf16x8*)&Al[(wm * 64 + i * 16 + l16) * 32 + lq * 8];
#pragma unroll
        for (int i = 0; i < 4; i++)
            bf[i] = *(const bf16x8*)&Bl[(wn * 64 + i * 16 + l16) * 32 + lq * 8];
#pragma unroll
        for (int mt = 0; mt < 4; mt++)
#pragma unroll
            for (int nt = 0; nt < 4; nt++)
                acc[mt][nt] = __builtin_amdgcn_mfma_f32_16x16x32_bf16(
                    af[mt], bf[nt], acc[mt][nt], 0, 0, 0);
    }
#pragma unroll
    for (int nt = 0; nt < 4; nt++) {
        int gcol = bn * 128 + wn * 64 + nt * 16 + l16;
        float bv = bias[gcol];
#pragma unroll
        for (int mt = 0; mt < 4; mt++) {
#pragma unroll
            for (int r = 0; r < 4; r++) {
                int grow = bm * 128 + wm * 64 + mt * 16 + lq * 4 + r;
                out[(size_t)grow * 1024 + gcol] = acc[mt][nt][r] + bv;
            }
        }
    }
}

// ---------------------------- flash attention ------------------------------
// grid: flat 512, block 256 (4 waves). Block bid handles bh = bid&63 and the
// q-tile PAIR (pr, 15-pr), pr = bid>>6, sequentially (128-row tiles).
// KVBLK=128: per staged tile, compute two 64-key halves sequentially.
// Per-block tiles = (pr+1) + (16-pr) = 17 — uniform across the grid.
// Two-barrier staging skeleton (R8-proven): barrier -> ds_write stage ->
// barrier -> global prefetch next tile -> compute both halves.
// Q pre-scaled so p = exp2(s). Row-sum via all-ones B-fragment.
// K staging: 8 lanes/row (128B rows), V staging: 16 lanes/row (256B rows) —
// both whole-row-per-lane-group, conflict-free.
__global__ __launch_bounds__(256) void attn_kernel(
    const __bf16* __restrict__ Q, const __bf16* __restrict__ K,
    const __bf16* __restrict__ Vt, __bf16* __restrict__ Y) {
    const int bid = blockIdx.x;
    const int pr = bid >> 6, bh = bid & 63;
    const int b = bh >> 4, h = bh & 15;
    int tid = threadIdx.x, w = tid >> 6, lane = tid & 63;
    int lq = lane >> 4, l16 = lane & 15;

    const __bf16* Qh = Q + (size_t)bh * Tn * DKn;
    const __bf16* Kh = K + (size_t)bh * Tn * DKn;
    const __bf16* Vh = Vt + (size_t)bh * DKn * Tn;  // [64 d][2048 t]

    __shared__ __bf16 Kl[128 * PAD];   // [key 0..127][d 0..63]
    __shared__ __bf16 Vl[64 * VPAD];   // [d 0..63][key 0..127]
    __shared__ __bf16 Pl[128 * PAD];   // P: C-layout write, A-layout read

    // staging: K = 128 rows x 128B (8 lanes/row, 4 passes of 32 rows)
    //          V = 64 rows x 256B (16 lanes/row, 4 passes of 16 rows)
    int skrow = tid >> 3, sksl = tid & 7;
    int svrow = tid >> 4, svsl = tid & 15;

    bf16x8 onesf;
#pragma unroll
    for (int j = 0; j < 8; j++) onesf[j] = (__bf16)1.0f;

    // prefetch 128-key tile 0 (shared by both segments' first iteration)
    bf16x8 kr[4], vr[4];
#pragma unroll
    for (int i = 0; i < 4; i++) {
        kr[i] = *(const bf16x8*)&Kh[(size_t)(skrow + i * 32) * 64 + sksl * 8];
        vr[i] = *(const bf16x8*)&Vh[(size_t)(svrow + i * 16) * 2048 + svsl * 8];
    }

#pragma unroll
    for (int seg = 0; seg < 2; seg++) {
        const int qt = seg ? (15 - pr) : pr;
        const int q0 = qt * 128;
        const int ktmax = qt;  // 128-key tiles 0..qt

        // Q fragments for this segment
        bf16x8 qf[2][2];
#pragma unroll
        for (int mt = 0; mt < 2; mt++)
#pragma unroll
            for (int ks = 0; ks < 2; ks++)
                qf[mt][ks] = *(const bf16x8*)&Qh[(size_t)(q0 + w * 32 + mt * 16 + l16) * 64 +
                                                 ks * 32 + lq * 8];

        floatx4 oacc[2][5] = {};  // [mt][d-tile 0..3, 4 = row-sum]

        for (int kt = 0; kt <= ktmax; kt++) {
            __syncthreads();  // all waves done reading Kl/Vl from previous iter
#pragma unroll
            for (int i = 0; i < 4; i++) {
                *(bf16x8*)&Kl[(skrow + i * 32) * PAD + sksl * 8] = kr[i];
                *(bf16x8*)&Vl[(svrow + i * 16) * VPAD + svsl * 8] = vr[i];
            }
            __syncthreads();
            // prefetch next 128-key tile (next kt, or segment-B tile 0)
            if (!(seg == 1 && kt == ktmax)) {
                int nk = (kt < ktmax) ? (kt + 1) : 0;
#pragma unroll
                for (int i = 0; i < 4; i++) {
                    kr[i] = *(const bf16x8*)&Kh[(size_t)(nk * 128 + skrow + i * 32) * 64 + sksl * 8];
                    vr[i] = *(const bf16x8*)&Vh[(size_t)(svrow + i * 16) * 2048 + nk * 128 + svsl * 8];
                }
            }

            // two 64-key halves from the staged 128-key tile
#pragma unroll
            for (int h2 = 0; h2 < 2; h2++) {
                // S = Q @ K^T   (Q pre-scaled)
                floatx4 s2[2][4] = {};
#pragma unroll
                for (int ks = 0; ks < 2; ks++) {
                    bf16x8 kf[4];
#pragma unroll
                    for (int nt = 0; nt < 4; nt++)
                        kf[nt] = *(const bf16x8*)&Kl[(h2 * 64 + nt * 16 + l16) * PAD +
                                                     ks * 32 + lq * 8];
#pragma unroll
                    for (int mt = 0; mt < 2; mt++)
#pragma unroll
                        for (int nt = 0; nt < 4; nt++)
                            s2[mt][nt] = __builtin_amdgcn_mfma_f32_16x16x32_bf16(
                                qf[mt][ks], kf[nt], s2[mt][nt], 0, 0, 0);
                }

                // causal mask on the diagonal 128-key tile
                if (kt == qt) {
#pragma unroll
                    for (int mt = 0; mt < 2; mt++)
#pragma unroll
                        for (int nt = 0; nt < 4; nt++) {
                            int col = kt * 128 + h2 * 64 + nt * 16 + l16;
#pragma unroll
                            for (int r = 0; r < 4; r++) {
                                int row = q0 + w * 32 + mt * 16 + lq * 4 + r;
                                if (col > row) s2[mt][nt][r] = MASK_NEG;
                            }
                        }
                }

                // p = exp2(s); write P (C-layout -> LDS, wave-private rows)
#pragma unroll
                for (int mt = 0; mt < 2; mt++) {
#pragma unroll
                    for (int nt = 0; nt < 4; nt++) {
#pragma unroll
                        for (int r = 0; r < 4; r++) {
                            float p = EXP2F(s2[mt][nt][r]);
                            int rowl = w * 32 + mt * 16 + lq * 4 + r;
                            Pl[rowl * PAD + nt * 16 + l16] = (__bf16)p;
                        }
                    }
                }

                // O += P @ [V | ones]
#pragma unroll
                for (int ks = 0; ks < 2; ks++) {
                    bf16x8 pf[2], vf[4];
#pragma unroll
                    for (int mt = 0; mt < 2; mt++)
                        pf[mt] = *(const bf16x8*)&Pl[(w * 32 + mt * 16 + l16) * PAD +
                                                     ks * 32 + lq * 8];
#pragma unroll
                    for (int dt = 0; dt < 4; dt++)
                        vf[dt] = *(const bf16x8*)&Vl[(dt * 16 + l16) * VPAD +
                                                     h2 * 64 + ks * 32 + lq * 8];
#pragma unroll
                    for (int mt = 0; mt < 2; mt++) {
#pragma unroll
                        for (int dt = 0; dt < 4; dt++)
                            oacc[mt][dt] = __builtin_amdgcn_mfma_f32_16x16x32_bf16(
                                pf[mt], vf[dt], oacc[mt][dt], 0, 0, 0);
                        oacc[mt][4] = __builtin_amdgcn_mfma_f32_16x16x32_bf16(
                            pf[mt], onesf, oacc[mt][4], 0, 0, 0);
                    }
                }
            }
        }

        // epilogue for this segment: tile 4 columns hold the row-sum.
#pragma unroll
        for (int mt = 0; mt < 2; mt++) {
#pragma unroll
            for (int r = 0; r < 4; r++) {
                float inv = 1.0f / oacc[mt][4][r];
                int rowg = q0 + w * 32 + mt * 16 + lq * 4 + r;
#pragma unroll
                for (int dt = 0; dt < 4; dt++)
                    Y[((size_t)(b * 2048 + rowg)) * 1024 + h * 64 + dt * 16 + l16] =
                        (__bf16)(oacc[mt][dt][r] * inv);
            }
        }
    }
}

// ------------------------------- launcher ----------------------------------

extern "C" void kernel_launch(void* const* d_in, const int* in_sizes, int n_in,
                              void* d_out, int out_size, void* d_ws, size_t ws_size,
                              hipStream_t stream) {
    const float* x     = (const float*)d_in[0];
    const float* Wqkv  = (const float*)d_in[1];
    const float* bqkv  = (const float*)d_in[2];
    const float* Wproj = (const float*)d_in[3];
    const float* bproj = (const float*)d_in[4];
    float* out = (float*)d_out;

    __bf16* xb     = (__bf16*)d_ws;                       // 8192*1024
    __bf16* WqkvT  = xb + (size_t)BT * Cn;                // 3072*1024
    __bf16* WprojT = WqkvT + (size_t)N_QKV * Cn;          // 1024*1024
    __bf16* Qb     = WprojT + (size_t)Cn * Cn;            // [b][h][t][64], pre-scaled
    __bf16* Kb     = Qb + (size_t)BT * Cn;                // [b][h][t][64]
    __bf16* Vb     = Kb + (size_t)BT * Cn;                // [b][h][64][t] (transposed)
    __bf16* Yb     = Vb + (size_t)BT * Cn;                // 8192*1024

    int nx = BT * Cn;
    cast_x_kernel<<<(nx / 4 + 255) / 256, 256, 0, stream>>>(x, xb, nx);
    transpose_cast_kernel<<<dim3(N_QKV / 32, Cn / 32), 256, 0, stream>>>(Wqkv, WqkvT, Cn, N_QKV);
    transpose_cast_kernel<<<dim3(Cn / 32, Cn / 32), 256, 0, stream>>>(Wproj, WprojT, Cn, Cn);

    gemm_qkv_kernel<<<dim3(N_QKV / 128, BT / 128), 256, 0, stream>>>(
        xb, WqkvT, bqkv, Qb, Kb, Vb);

    attn_kernel<<<dim3(512), 256, 0, stream>>>(Qb, Kb, Vb, Yb);

    gemm_proj_kernel<<<dim3(Cn / 128, BT / 128), 256, 0, stream>>>(
        Yb, WprojT, bproj, out);
}

// Round 5
// 246.866 us; speedup vs baseline: 1.4265x; 1.0346x over previous
//
#include <hip/hip_runtime.h>
#include <stdint.h>

// ---------------------------------------------------------------------------
// CausalSelfAttention: x[4,2048,1024] fp32 -> out fp32
// bf16 MFMA (16x16x32) everywhere, fp32 accum.
// R13: GEMMs BK 32->64 + XOR LDS swizzle (T2, both-sides via pre-swizzled
//      global source for global_load_lds; read blk = (ks*4+lq)^(l16&7)).
//      Halves barrier sections (32->16) and kills the 8-way bank conflict
//      (6.29M/dispatch measured in R12). attn unchanged from R12 (KVBLK=128).
//      GEMM grid swizzle (T1) kept from R11.
// ---------------------------------------------------------------------------

typedef float  floatx4 __attribute__((ext_vector_type(4)));
typedef __bf16 bf16x8  __attribute__((ext_vector_type(8)));
typedef __bf16 bf16x4  __attribute__((ext_vector_type(4)));

#define AS1 __attribute__((address_space(1)))
#define AS3 __attribute__((address_space(3)))

__device__ __forceinline__ void gload_lds16(const void* g, void* l) {
    __builtin_amdgcn_global_load_lds((AS1 void*)(uintptr_t)g,
                                     (AS3 void*)(uintptr_t)l, 16, 0, 0);
}

#if __has_builtin(__builtin_amdgcn_exp2f)
#define EXP2F(x) __builtin_amdgcn_exp2f(x)   // raw v_exp_f32
#else
#define EXP2F(x) exp2f(x)
#endif

#define LOG2E 1.44269504088896340736f
#define ATT_SC (0.125f * LOG2E)   // softmax scale folded into Q at GEMM1
#define MASK_NEG (-3.0e4f)        // exp2(-3e4) == 0, safely finite

static constexpr int Bn = 4, Tn = 2048, Cn = 1024, Hn = 16, DKn = 64;
static constexpr int BT = Bn * Tn;          // 8192
static constexpr int N_QKV = 3 * Cn;        // 3072
static constexpr int PAD = 68;              // LDS row pad for 64-wide rows
static constexpr int VPAD = 132;            // LDS row pad for 128-wide rows

// ------------------------- cast / transpose kernels ------------------------

__global__ void cast_x_kernel(const float* __restrict__ x, __bf16* __restrict__ xb, int n) {
    int i = (blockIdx.x * blockDim.x + threadIdx.x) * 4;
    if (i < n) {
        float4 v = *(const float4*)(x + i);
        bf16x4 o;
        o[0] = (__bf16)v.x; o[1] = (__bf16)v.y; o[2] = (__bf16)v.z; o[3] = (__bf16)v.w;
        *(bf16x4*)(xb + i) = o;
    }
}

// W [R][C] fp32 -> WT [C][R] bf16
__global__ void transpose_cast_kernel(const float* __restrict__ W, __bf16* __restrict__ WT,
                                      int R, int C) {
    __shared__ float tile[32][33];
    int tx = threadIdx.x & 31, ty = threadIdx.x >> 5;  // 32 x 8
    int r0 = blockIdx.y * 32, c0 = blockIdx.x * 32;
#pragma unroll
    for (int i = 0; i < 4; i++)
        tile[ty + i * 8][tx] = W[(size_t)(r0 + ty + i * 8) * C + c0 + tx];
    __syncthreads();
#pragma unroll
    for (int i = 0; i < 4; i++)
        WT[(size_t)(c0 + ty + i * 8) * R + r0 + tx] = (__bf16)tile[tx][ty + i * 8];
}

// T1: bijective XCD-aware remap of the flattened block id. nwg % 8 == 0 for
// both GEMMs (1536, 512).
__device__ __forceinline__ void xcd_swizzle(int gx, int* bn, int* bm) {
    int flat = blockIdx.y * gx + blockIdx.x;
    int nwg = gx * gridDim.y;
    int cpx = nwg >> 3;
    int swz = (flat & 7) * cpx + (flat >> 3);
    *bm = swz / gx;
    *bn = swz - *bm * gx;
}

// ------------------------------- GEMM 1 ------------------------------------
// C[8192,3072] = A[8192,1024] @ Bt[3072,1024]^T + bias.  BK=64, swizzled LDS.
// Q (pre-scaled by ATT_SC), K -> head-major [b][h][t][64];
// V -> TRANSPOSED head-major [b][h][64][t].
__global__ __launch_bounds__(256) void gemm_qkv_kernel(
    const __bf16* __restrict__ A, const __bf16* __restrict__ Bt,
    const float* __restrict__ bias,
    __bf16* __restrict__ Qo, __bf16* __restrict__ Ko, __bf16* __restrict__ Vo) {
    const int K = 1024;
    __shared__ __bf16 Al[128 * 64];
    __shared__ __bf16 Bl[128 * 64];
    int tid = threadIdx.x, w = tid >> 6, lane = tid & 63;
    int lq = lane >> 4, l16 = lane & 15;
    int bm, bn;
    xcd_swizzle(gridDim.x, &bn, &bm);
    int wm = w & 1, wn = w >> 1;  // 2x2 waves -> 64x64 each

    // Staging: wave stages 32 rows x 64 cols (128B rows) per matrix, 4 calls
    // of 8 rows. Global col-block pre-swizzled: LDS(r,cb) holds global block
    // cb ^ (r&7) (r&7 == (lane>>3)&7 since row bases are multiples of 8).
    int srow = lane >> 3;                 // row within 8-row group
    int scb  = (lane & 7) ^ (srow & 7);   // pre-swizzled global col-block
    const __bf16* Ag = A + (size_t)(bm * 128 + w * 32 + srow) * K + scb * 8;
    const __bf16* Bg = Bt + (size_t)(bn * 128 + w * 32 + srow) * K + scb * 8;
    __bf16* AlW = Al + w * 32 * 64;
    __bf16* BlW = Bl + w * 32 * 64;

    // Read-side swizzled element offsets (per ks half). (row&7) == (l16&7).
    const int co0 = ((0 * 4 + lq) ^ (l16 & 7)) * 8;
    const int co1 = ((1 * 4 + lq) ^ (l16 & 7)) * 8;

    floatx4 acc[4][4] = {};
    for (int k0 = 0; k0 < K; k0 += 64) {
        __syncthreads();
#pragma unroll
        for (int c = 0; c < 4; c++) {
            gload_lds16(Ag + k0 + (size_t)c * 8 * K, AlW + c * 8 * 64);
            gload_lds16(Bg + k0 + (size_t)c * 8 * K, BlW + c * 8 * 64);
        }
        __syncthreads();
#pragma unroll
        for (int ks = 0; ks < 2; ks++) {
            const int co = ks ? co1 : co0;
            bf16x8 af[4], bf[4];
#pragma unroll
            for (int i = 0; i < 4; i++)
                af[i] = *(const bf16x8*)&Al[(wm * 64 + i * 16 + l16) * 64 + co];
#pragma unroll
            for (int i = 0; i < 4; i++)
                bf[i] = *(const bf16x8*)&Bl[(wn * 64 + i * 16 + l16) * 64 + co];
#pragma unroll
            for (int mt = 0; mt < 4; mt++)
#pragma unroll
                for (int nt = 0; nt < 4; nt++)
                    acc[mt][nt] = __builtin_amdgcn_mfma_f32_16x16x32_bf16(
                        af[mt], bf[nt], acc[mt][nt], 0, 0, 0);
        }
    }
    // epilogue: C/D layout col=l16, row=lq*4+r.
#pragma unroll
    for (int nt = 0; nt < 4; nt++) {
        int gbase = bn * 128 + wn * 64 + nt * 16;  // wave-uniform, 16-aligned
        int gcol = gbase + l16;
        int which = gbase >> 10;                   // uniform (1024 % 16 == 0)
        float bv = bias[gcol];
        if (which == 2) {
            // V transposed: [b][h][64 d][2048 t], 4 consecutive t per lane.
            int hh = (gbase - 2048) >> 6;
            int dd = ((gbase - 2048) & 63) + l16;
#pragma unroll
            for (int mt = 0; mt < 4; mt++) {
                int growb = bm * 128 + wm * 64 + mt * 16 + lq * 4;
                int bb = growb >> 11, tt = growb & 2047;
                bf16x4 v4;
#pragma unroll
                for (int r = 0; r < 4; r++) v4[r] = (__bf16)(acc[mt][nt][r] + bv);
                *(bf16x4*)&Vo[((size_t)(bb * 16 + hh) * 64 + dd) * 2048 + tt] = v4;
            }
        } else {
            int rem = gbase & 1023;
            int hh = rem >> 6, dd = (rem & 63) + l16;
            __bf16* dst = (which == 0) ? Qo : Ko;
            float scl = (which == 0) ? ATT_SC : 1.0f;  // fold softmax scale into Q
#pragma unroll
            for (int mt = 0; mt < 4; mt++) {
#pragma unroll
                for (int r = 0; r < 4; r++) {
                    int grow = bm * 128 + wm * 64 + mt * 16 + lq * 4 + r;
                    int bb = grow >> 11, tt = grow & 2047;
                    dst[((size_t)(bb * 16 + hh) * 2048 + tt) * 64 + dd] =
                        (__bf16)((acc[mt][nt][r] + bv) * scl);
                }
            }
        }
    }
}

// ------------------------------- GEMM 2 ------------------------------------
__global__ __launch_bounds__(256) void gemm_proj_kernel(
    const __bf16* __restrict__ A, const __bf16* __restrict__ Bt,
    const float* __restrict__ bias, float* __restrict__ out) {
    const int K = 1024;
    __shared__ __bf16 Al[128 * 64];
    __shared__ __bf16 Bl[128 * 64];
    int tid = threadIdx.x, w = tid >> 6, lane = tid & 63;
    int lq = lane >> 4, l16 = lane & 15;
    int bm, bn;
    xcd_swizzle(gridDim.x, &bn, &bm);
    int wm = w & 1, wn = w >> 1;

    int srow = lane >> 3;
    int scb  = (lane & 7) ^ (srow & 7);
    const __bf16* Ag = A + (size_t)(bm * 128 + w * 32 + srow) * K + scb * 8;
    const __bf16* Bg = Bt + (size_t)(bn * 128 + w * 32 + srow) * K + scb * 8;
    __bf16* AlW = Al + w * 32 * 64;
    __bf16* BlW = Bl + w * 32 * 64;

    const int co0 = ((0 * 4 + lq) ^ (l16 & 7)) * 8;
    const int co1 = ((1 * 4 + lq) ^ (l16 & 7)) * 8;

    floatx4 acc[4][4] = {};
    for (int k0 = 0; k0 < K; k0 += 64) {
        __syncthreads();
#pragma unroll
        for (int c = 0; c < 4; c++) {
            gload_lds16(Ag + k0 + (size_t)c * 8 * K, AlW + c * 8 * 64);
            gload_lds16(Bg + k0 + (size_t)c * 8 * K, BlW + c * 8 * 64);
        }
        __syncthreads();
#pragma unroll
        for (int ks = 0; ks < 2; ks++) {
            const int co = ks ? co1 : co0;
            bf16x8 af[4], bf[4];
#pragma unroll
            for (int i = 0; i < 4; i++)
                af[i] = *(const bf16x8*)&Al[(wm * 64 + i * 16 + l16) * 64 + co];
#pragma unroll
            for (int i = 0; i < 4; i++)
                bf[i] = *(const bf16x8*)&Bl[(wn * 64 + i * 16 + l16) * 64 + co];
#pragma unroll
            for (int mt = 0; mt < 4; mt++)
#pragma unroll
                for (int nt = 0; nt < 4; nt++)
                    acc[mt][nt] = __builtin_amdgcn_mfma_f32_16x16x32_bf16(
                        af[mt], bf[nt], acc[mt][nt], 0, 0, 0);
        }
    }
#pragma unroll
    for (int nt = 0; nt < 4; nt++) {
        int gcol = bn * 128 + wn * 64 + nt * 16 + l16;
        float bv = bias[gcol];
#pragma unroll
        for (int mt = 0; mt < 4; mt++) {
#pragma unroll
            for (int r = 0; r < 4; r++) {
                int grow = bm * 128 + wm * 64 + mt * 16 + lq * 4 + r;
                out[(size_t)grow * 1024 + gcol] = acc[mt][nt][r] + bv;
            }
        }
    }
}

// ---------------------------- flash attention ------------------------------
// Unchanged from R12 (KVBLK=128, two-barrier skeleton, uniform 17 tiles/blk).
__global__ __launch_bounds__(256) void attn_kernel(
    const __bf16* __restrict__ Q, const __bf16* __restrict__ K,
    const __bf16* __restrict__ Vt, __bf16* __restrict__ Y) {
    const int bid = blockIdx.x;
    const int pr = bid >> 6, bh = bid & 63;
    const int b = bh >> 4, h = bh & 15;
    int tid = threadIdx.x, w = tid >> 6, lane = tid & 63;
    int lq = lane >> 4, l16 = lane & 15;

    const __bf16* Qh = Q + (size_t)bh * Tn * DKn;
    const __bf16* Kh = K + (size_t)bh * Tn * DKn;
    const __bf16* Vh = Vt + (size_t)bh * DKn * Tn;  // [64 d][2048 t]

    __shared__ __bf16 Kl[128 * PAD];   // [key 0..127][d 0..63]
    __shared__ __bf16 Vl[64 * VPAD];   // [d 0..63][key 0..127]
    __shared__ __bf16 Pl[128 * PAD];   // P: C-layout write, A-layout read

    int skrow = tid >> 3, sksl = tid & 7;
    int svrow = tid >> 4, svsl = tid & 15;

    bf16x8 onesf;
#pragma unroll
    for (int j = 0; j < 8; j++) onesf[j] = (__bf16)1.0f;

    bf16x8 kr[4], vr[4];
#pragma unroll
    for (int i = 0; i < 4; i++) {
        kr[i] = *(const bf16x8*)&Kh[(size_t)(skrow + i * 32) * 64 + sksl * 8];
        vr[i] = *(const bf16x8*)&Vh[(size_t)(svrow + i * 16) * 2048 + svsl * 8];
    }

#pragma unroll
    for (int seg = 0; seg < 2; seg++) {
        const int qt = seg ? (15 - pr) : pr;
        const int q0 = qt * 128;
        const int ktmax = qt;  // 128-key tiles 0..qt

        bf16x8 qf[2][2];
#pragma unroll
        for (int mt = 0; mt < 2; mt++)
#pragma unroll
            for (int ks = 0; ks < 2; ks++)
                qf[mt][ks] = *(const bf16x8*)&Qh[(size_t)(q0 + w * 32 + mt * 16 + l16) * 64 +
                                                 ks * 32 + lq * 8];

        floatx4 oacc[2][5] = {};  // [mt][d-tile 0..3, 4 = row-sum]

        for (int kt = 0; kt <= ktmax; kt++) {
            __syncthreads();
#pragma unroll
            for (int i = 0; i < 4; i++) {
                *(bf16x8*)&Kl[(skrow + i * 32) * PAD + sksl * 8] = kr[i];
                *(bf16x8*)&Vl[(svrow + i * 16) * VPAD + svsl * 8] = vr[i];
            }
            __syncthreads();
            if (!(seg == 1 && kt == ktmax)) {
                int nk = (kt < ktmax) ? (kt + 1) : 0;
#pragma unroll
                for (int i = 0; i < 4; i++) {
                    kr[i] = *(const bf16x8*)&Kh[(size_t)(nk * 128 + skrow + i * 32) * 64 + sksl * 8];
                    vr[i] = *(const bf16x8*)&Vh[(size_t)(svrow + i * 16) * 2048 + nk * 128 + svsl * 8];
                }
            }

#pragma unroll
            for (int h2 = 0; h2 < 2; h2++) {
                floatx4 s2[2][4] = {};
#pragma unroll
                for (int ks = 0; ks < 2; ks++) {
                    bf16x8 kf[4];
#pragma unroll
                    for (int nt = 0; nt < 4; nt++)
                        kf[nt] = *(const bf16x8*)&Kl[(h2 * 64 + nt * 16 + l16) * PAD +
                                                     ks * 32 + lq * 8];
#pragma unroll
                    for (int mt = 0; mt < 2; mt++)
#pragma unroll
                        for (int nt = 0; nt < 4; nt++)
                            s2[mt][nt] = __builtin_amdgcn_mfma_f32_16x16x32_bf16(
                                qf[mt][ks], kf[nt], s2[mt][nt], 0, 0, 0);
                }

                if (kt == qt) {
#pragma unroll
                    for (int mt = 0; mt < 2; mt++)
#pragma unroll
                        for (int nt = 0; nt < 4; nt++) {
                            int col = kt * 128 + h2 * 64 + nt * 16 + l16;
#pragma unroll
                            for (int r = 0; r < 4; r++) {
                                int row = q0 + w * 32 + mt * 16 + lq * 4 + r;
                                if (col > row) s2[mt][nt][r] = MASK_NEG;
                            }
                        }
                }

#pragma unroll
                for (int mt = 0; mt < 2; mt++) {
#pragma unroll
                    for (int nt = 0; nt < 4; nt++) {
#pragma unroll
                        for (int r = 0; r < 4; r++) {
                            float p = EXP2F(s2[mt][nt][r]);
                            int rowl = w * 32 + mt * 16 + lq * 4 + r;
                            Pl[rowl * PAD + nt * 16 + l16] = (__bf16)p;
                        }
                    }
                }

#pragma unroll
                for (int ks = 0; ks < 2; ks++) {
                    bf16x8 pf[2], vf[4];
#pragma unroll
                    for (int mt = 0; mt < 2; mt++)
                        pf[mt] = *(const bf16x8*)&Pl[(w * 32 + mt * 16 + l16) * PAD +
                                                     ks * 32 + lq * 8];
#pragma unroll
                    for (int dt = 0; dt < 4; dt++)
                        vf[dt] = *(const bf16x8*)&Vl[(dt * 16 + l16) * VPAD +
                                                     h2 * 64 + ks * 32 + lq * 8];
#pragma unroll
                    for (int mt = 0; mt < 2; mt++) {
#pragma unroll
                        for (int dt = 0; dt < 4; dt++)
                            oacc[mt][dt] = __builtin_amdgcn_mfma_f32_16x16x32_bf16(
                                pf[mt], vf[dt], oacc[mt][dt], 0, 0, 0);
                        oacc[mt][4] = __builtin_amdgcn_mfma_f32_16x16x32_bf16(
                            pf[mt], onesf, oacc[mt][4], 0, 0, 0);
                    }
                }
            }
        }

#pragma unroll
        for (int mt = 0; mt < 2; mt++) {
#pragma unroll
            for (int r = 0; r < 4; r++) {
                float inv = 1.0f / oacc[mt][4][r];
                int rowg = q0 + w * 32 + mt * 16 + lq * 4 + r;
#pragma unroll
                for (int dt = 0; dt < 4; dt++)
                    Y[((size_t)(b * 2048 + rowg)) * 1024 + h * 64 + dt * 16 + l16] =
                        (__bf16)(oacc[mt][dt][r] * inv);
            }
        }
    }
}

// ------------------------------- launcher ----------------------------------

extern "C" void kernel_launch(void* const* d_in, const int* in_sizes, int n_in,
                              void* d_out, int out_size, void* d_ws, size_t ws_size,
                              hipStream_t stream) {
    const float* x     = (const float*)d_in[0];
    const float* Wqkv  = (const float*)d_in[1];
    const float* bqkv  = (const float*)d_in[2];
    const float* Wproj = (const float*)d_in[3];
    const float* bproj = (const float*)d_in[4];
    float* out = (float*)d_out;

    __bf16* xb     = (__bf16*)d_ws;                       // 8192*1024
    __bf16* WqkvT  = xb + (size_t)BT * Cn;                // 3072*1024
    __bf16* WprojT = WqkvT + (size_t)N_QKV * Cn;          // 1024*1024
    __bf16* Qb     = WprojT + (size_t)Cn * Cn;            // [b][h][t][64], pre-scaled
    __bf16* Kb     = Qb + (size_t)BT * Cn;                // [b][h][t][64]
    __bf16* Vb     = Kb + (size_t)BT * Cn;                // [b][h][64][t] (transposed)
    __bf16* Yb     = Vb + (size_t)BT * Cn;                // 8192*1024

    int nx = BT * Cn;
    cast_x_kernel<<<(nx / 4 + 255) / 256, 256, 0, stream>>>(x, xb, nx);
    transpose_cast_kernel<<<dim3(N_QKV / 32, Cn / 32), 256, 0, stream>>>(Wqkv, WqkvT, Cn, N_QKV);
    transpose_cast_kernel<<<dim3(Cn / 32, Cn / 32), 256, 0, stream>>>(Wproj, WprojT, Cn, Cn);

    gemm_qkv_kernel<<<dim3(N_QKV / 128, BT / 128), 256, 0, stream>>>(
        xb, WqkvT, bqkv, Qb, Kb, Vb);

    attn_kernel<<<dim3(512), 256, 0, stream>>>(Qb, Kb, Vb, Yb);

    gemm_proj_kernel<<<dim3(Cn / 128, BT / 128), 256, 0, stream>>>(
        Yb, WprojT, bproj, out);
}